// Round 1
// baseline (399.122 us; speedup 1.0000x reference)
//
#include <hip/hip_runtime.h>
#include <math.h>

#define BB 4096
#define LL 200
#define HH 32
#define PF 8      // prefetch depth (outstanding global loads per wave)

// ---------------------------------------------------------------------------
// R4: decouple the 210-MB local_states stream from the MLP.
//   Kernel A: 128-thr blocks, 1 row/block, 2 waves/row (25 chunks each).
//             8192 waves -> 32 waves/CU cap; __launch_bounds__(128,8)
//             forces <=64 VGPR so the VGPR cap is also 32 waves/CU.
//             Writes relu'd states[b][64] to workspace.
//   Kernel B: previous phase-B MLP (1024 x 256), reads states from ws.
// R3 post-mortem: fused kernel was latency-bound (VALUBusy 14%, occ 28%,
// 1.5 TB/s effective): one wave per row caps waves/CU at 16 and VGPR=68
// (phase-B w[64]) halves the VGPR occupancy cap. Splitting fixes both.
// ---------------------------------------------------------------------------

__global__ __launch_bounds__(128, 8) void actor_stream_kernel(
    const float* __restrict__ gs,
    const float* __restrict__ ls,
    const float* __restrict__ W_w, const float* __restrict__ W_b,
    const float* __restrict__ U_w, const float* __restrict__ U_b,
    const float* __restrict__ att_w, const float* __restrict__ att_b,
    float* __restrict__ states)
{
    __shared__ float c_lds[64];
    __shared__ __align__(16) float y_part[2][64];
    __shared__ float S_part[2];
    __shared__ __align__(16) float y_lds[64];

    const int tid  = threadIdx.x;
    const int lane = tid & 63;
    const int wid  = tid >> 6;       // 0..1: which half of the row
    const int b    = blockIdx.x;

    const int h    = lane & 31;      // owned hidden unit (both halves)
    const int half = lane >> 5;      // d-half for 64-d dots

    // ---- wg[h] = gs[b].W_w[h] + W_b[h]; halves split d, xor32 combine ----
    const float4* g4 = (const float4*)(gs + (size_t)b * 64);
    const float4* W4 = (const float4*)(W_w);
    float wg = (half == 0) ? W_b[h] : 0.f;
    #pragma unroll
    for (int dd = 0; dd < 8; ++dd) {
        float4 gv = g4[half * 8 + dd];
        float4 wv = W4[h * 16 + half * 8 + dd];
        wg += gv.x * wv.x + gv.y * wv.y + gv.z * wv.z + gv.w * wv.w;
    }
    wg += __shfl_xor(wg, 32);        // all lanes now hold wg[h]

    // ---- gt = wg.a_g ; t2 = wg.a_l (butterfly over h within 32-halves) ----
    float gt = wg * att_w[h];
    float t2 = wg * att_w[HH + h];
    #pragma unroll
    for (int m = 1; m < 32; m <<= 1) {
        gt += __shfl_xor(gt, m);
        t2 += __shfl_xor(t2, m);
    }
    const float attb = att_b[0];
    const float lin0 = gt + t2 + attb;
    const float s0   = (lin0 > 0.f) ? lin0 : 0.01f * lin0;

    // ---- c[d] = sum_h a_l[h]*U_w[h][d]  (lane owns d=lane) ----
    float c = 0.f;
    float ubal = 0.f;
    #pragma unroll
    for (int hh = 0; hh < HH; ++hh) {
        const float alh = att_w[HH + hh];      // uniform -> s_load
        c    += alh * U_w[hh * 64 + lane];     // coalesced, L1-hot
        ubal += alh * U_b[hh];
    }
    if (wid == 0) c_lds[lane] = c;
    __syncthreads();
    const int q = lane & 15;
    const float4 cq = *(const float4*)&c_lds[4 * q];
    const float base = gt + ubal + attb;

    // ---- stream this wave's 100 l-rows: 25 chunks, depth-PF ring ----
    // wave w covers l in [w*100, w*100+100): 1600 float4, 64/chunk.
    const float4* xs = (const float4*)(ls + (size_t)b * (LL * 64)) + wid * 1600;
    float4 yx = make_float4(0.f, 0.f, 0.f, 0.f);
    float Sacc = 0.f;

    float4 Xbuf[PF];
    #pragma unroll
    for (int i = 0; i < PF; ++i)
        Xbuf[i] = xs[lane + i * 64];

    #pragma unroll                    // FULL unroll: ring index compile-time
    for (int t = 0; t < 25; ++t) {
        float4 X = Xbuf[t & (PF - 1)];
        int tn = t + PF;
        if (tn > 24) tn = 24;         // clamped redundant tail (L1-hot)
        Xbuf[t & (PF - 1)] = xs[lane + tn * 64];

        float p = X.x * cq.x + X.y * cq.y + X.z * cq.z + X.w * cq.w;
        p += __shfl_xor(p, 1);
        p += __shfl_xor(p, 2);
        p += __shfl_xor(p, 4);
        p += __shfl_xor(p, 8);        // 16-lane group dot: x[l].c
        const float linv = p + base;
        const float sl = (linv > 0.f) ? linv : 0.01f * linv;
        yx.x += sl * X.x;
        yx.y += sl * X.y;
        yx.z += sl * X.z;
        yx.w += sl * X.w;
        Sacc += sl;                   // identical across the 16-lane group
    }

    // ---- combine the 4 l-groups within the wave ----
    #pragma unroll
    for (int m = 16; m < 64; m <<= 1) {
        yx.x += __shfl_xor(yx.x, m);
        yx.y += __shfl_xor(yx.y, m);
        yx.z += __shfl_xor(yx.z, m);
        yx.w += __shfl_xor(yx.w, m);
        Sacc += __shfl_xor(Sacc, m);
    }
    if (lane < 16) *(float4*)&y_part[wid][4 * q] = yx;
    if (lane == 0) S_part[wid] = Sacc;
    __syncthreads();

    // ---- combine the 2 wave halves ----
    if (tid < 16) {
        float4 ya = *(const float4*)&y_part[0][4 * tid];
        float4 yb = *(const float4*)&y_part[1][4 * tid];
        ya.x += yb.x; ya.y += yb.y; ya.z += yb.z; ya.w += yb.w;
        *(float4*)&y_lds[4 * tid] = ya;
    }
    __syncthreads();

    // ---- V[h] = U_w[h].y + U_b[h]*S ; states -> global (wave 0 only) ----
    if (wid == 0) {
        const float Stot = S_part[0] + S_part[1];
        float V = (half == 0) ? (U_b[h] * Stot) : 0.f;
        const float4* U4 = (const float4*)U_w;
        const float4* y4 = (const float4*)y_lds;
        #pragma unroll
        for (int dd = 0; dd < 8; ++dd) {
            float4 uv = U4[h * 16 + half * 8 + dd];
            float4 yv = y4[half * 8 + dd];
            V += uv.x * yv.x + uv.y * yv.y + uv.z * yv.z + uv.w * yv.w;
        }
        V += __shfl_xor(V, 32);       // all lanes hold full V[h]

        const float total = s0 + Stot;
        const float n0    = s0 / total;
        const float outv  = (lane < 32) ? (n0 * wg) : (V / total);
        states[(size_t)b * 64 + lane] = fmaxf(outv, 0.f);
    }
}

// ---------------------------------------------------------------------------
// Kernel B: MLP 64->256->256->8, relu/relu/sigmoid. 4 rows per 256-thr block.
// ---------------------------------------------------------------------------
__global__ __launch_bounds__(256) void actor_mlp_kernel(
    const float* __restrict__ states,
    const float* __restrict__ l1_w, const float* __restrict__ l1_b,
    const float* __restrict__ l2_w, const float* __restrict__ l2_b,
    const float* __restrict__ l3_w, const float* __restrict__ l3_b,
    float* __restrict__ out)
{
    __shared__ __align__(16) float s_x [4 * 64];
    __shared__ __align__(16) float s_a1[4 * 256];
    __shared__ __align__(16) float s_a2[4 * 260];  // pad 260: float4-able, conflict-free

    const int tid = threadIdx.x;

    s_x[tid] = states[(size_t)blockIdx.x * 256 + tid];  // 4 rows x 64, coalesced
    __syncthreads();

    float w[64];

    // ---- layer 1: thread owns unit tid; weight row in VGPRs ----
    {
        const float* wr = l1_w + tid * 64;
        #pragma unroll
        for (int d = 0; d < 64; ++d) w[d] = wr[d];
        float bias = l1_b[tid];
        #pragma unroll
        for (int r = 0; r < 4; ++r) {
            float acc = bias;
            #pragma unroll
            for (int d = 0; d < 64; ++d)
                acc += s_x[r * 64 + d] * w[d];   // LDS broadcast
            s_a1[r * 256 + tid] = fmaxf(acc, 0.f);
        }
    }
    __syncthreads();

    // ---- layer 2 ----
    {
        float acc[4];
        float bias = l2_b[tid];
        #pragma unroll
        for (int r = 0; r < 4; ++r) acc[r] = bias;
        for (int kc = 0; kc < 4; ++kc) {
            const float* wr = l2_w + tid * 256 + kc * 64;
            #pragma unroll
            for (int d = 0; d < 64; ++d) w[d] = wr[d];
            #pragma unroll
            for (int r = 0; r < 4; ++r) {
                #pragma unroll
                for (int d = 0; d < 64; ++d)
                    acc[r] += s_a1[r * 256 + kc * 64 + d] * w[d];
            }
        }
        #pragma unroll
        for (int r = 0; r < 4; ++r)
            s_a2[r * 260 + tid] = fmaxf(acc[r], 0.f);
    }
    __syncthreads();

    // ---- layer 3 + sigmoid: threads 0..31, float4 LDS reads ----
    if (tid < 32) {
        int r = tid >> 3, o = tid & 7;
        float acc = l3_b[o];
        const float4* wr4 = (const float4*)(l3_w + o * 256);
        const float4* a4  = (const float4*)&s_a2[r * 260];
        #pragma unroll 8
        for (int k = 0; k < 64; ++k) {
            float4 av = a4[k];
            float4 wv = wr4[k];
            acc += av.x * wv.x + av.y * wv.y + av.z * wv.z + av.w * wv.w;
        }
        out[(size_t)(blockIdx.x * 4 + r) * 8 + o] =
            1.f / (1.f + __expf(-acc));   // MAX_ACTION = 1
    }
}

// ---------------------------------------------------------------------------
// Fallback: previous fused kernel (used only if ws_size is too small).
// ---------------------------------------------------------------------------
__global__ __launch_bounds__(256) void actor_fused_kernel(
    const float* __restrict__ gs,
    const float* __restrict__ ls,
    const float* __restrict__ W_w, const float* __restrict__ W_b,
    const float* __restrict__ U_w, const float* __restrict__ U_b,
    const float* __restrict__ att_w, const float* __restrict__ att_b,
    const float* __restrict__ l1_w, const float* __restrict__ l1_b,
    const float* __restrict__ l2_w, const float* __restrict__ l2_b,
    const float* __restrict__ l3_w, const float* __restrict__ l3_b,
    float* __restrict__ out)
{
    __shared__ float c_lds[4 * 64];
    __shared__ float y_lds[4 * 64];
    __shared__ __align__(16) float s_x [4 * 64];
    __shared__ __align__(16) float s_a1[4 * 256];
    __shared__ __align__(16) float s_a2[4 * 260];

    const int tid  = threadIdx.x;
    const int lane = tid & 63;
    const int wid  = tid >> 6;
    const int b    = blockIdx.x * 4 + wid;

    const int h    = lane & 31;
    const int half = lane >> 5;
    const int q    = lane & 15;
    const int lg   = lane >> 4;

    const float4* g4 = (const float4*)(gs + (size_t)b * 64);
    const float4* W4 = (const float4*)(W_w);
    float wg = (half == 0) ? W_b[h] : 0.f;
    #pragma unroll
    for (int dd = 0; dd < 8; ++dd) {
        float4 gv = g4[half * 8 + dd];
        float4 wv = W4[h * 16 + half * 8 + dd];
        wg += gv.x * wv.x + gv.y * wv.y + gv.z * wv.z + gv.w * wv.w;
    }
    wg += __shfl_xor(wg, 32);

    float gt = wg * att_w[h];
    float t2 = wg * att_w[HH + h];
    #pragma unroll
    for (int m = 1; m < 32; m <<= 1) {
        gt += __shfl_xor(gt, m);
        t2 += __shfl_xor(t2, m);
    }
    const float attb = att_b[0];
    const float lin0 = gt + t2 + attb;
    const float s0   = (lin0 > 0.f) ? lin0 : 0.01f * lin0;

    float c = 0.f;
    float ubal = 0.f;
    #pragma unroll
    for (int hh = 0; hh < HH; ++hh) {
        const float alh = att_w[HH + hh];
        c    += alh * U_w[hh * 64 + lane];
        ubal += alh * U_b[hh];
    }
    c_lds[wid * 64 + lane] = c;
    __syncthreads();
    const float4 cq = *(const float4*)&c_lds[wid * 64 + 4 * q];
    const float base = gt + ubal + attb;

    const float4* xs = (const float4*)(ls + (size_t)b * (LL * 64));
    const int idx0 = lg * 16 + q;
    float4 yx = make_float4(0.f, 0.f, 0.f, 0.f);
    float Sacc = 0.f;

    float4 Xbuf[PF];
    #pragma unroll
    for (int i = 0; i < PF; ++i)
        Xbuf[i] = xs[idx0 + i * 64];

    #pragma unroll
    for (int t = 0; t < 50; ++t) {
        float4 X = Xbuf[t & (PF - 1)];
        int tn = t + PF;
        if (tn > 49) tn = 49;
        Xbuf[t & (PF - 1)] = xs[idx0 + tn * 64];

        float p = X.x * cq.x + X.y * cq.y + X.z * cq.z + X.w * cq.w;
        p += __shfl_xor(p, 1);
        p += __shfl_xor(p, 2);
        p += __shfl_xor(p, 4);
        p += __shfl_xor(p, 8);
        const float linv = p + base;
        const float sl = (linv > 0.f) ? linv : 0.01f * linv;
        yx.x += sl * X.x;
        yx.y += sl * X.y;
        yx.z += sl * X.z;
        yx.w += sl * X.w;
        Sacc += sl;
    }

    #pragma unroll
    for (int m = 16; m < 64; m <<= 1) {
        yx.x += __shfl_xor(yx.x, m);
        yx.y += __shfl_xor(yx.y, m);
        yx.z += __shfl_xor(yx.z, m);
        yx.w += __shfl_xor(yx.w, m);
        Sacc += __shfl_xor(Sacc, m);
    }
    if (lane < 16) *(float4*)&y_lds[wid * 64 + 4 * q] = yx;
    __syncthreads();

    float V = (half == 0) ? (U_b[h] * Sacc) : 0.f;
    const float4* U4 = (const float4*)U_w;
    const float4* y4 = (const float4*)&y_lds[wid * 64];
    #pragma unroll
    for (int dd = 0; dd < 8; ++dd) {
        float4 uv = U4[h * 16 + half * 8 + dd];
        float4 yv = y4[half * 8 + dd];
        V += uv.x * yv.x + uv.y * yv.y + uv.z * yv.z + uv.w * yv.w;
    }
    V += __shfl_xor(V, 32);

    const float total = s0 + Sacc;
    const float n0    = s0 / total;
    const float outv  = (lane < 32) ? (n0 * wg) : (V / total);
    s_x[wid * 64 + lane] = fmaxf(outv, 0.f);
    __syncthreads();

    float w[64];
    {
        const float* wr = l1_w + tid * 64;
        #pragma unroll
        for (int d = 0; d < 64; ++d) w[d] = wr[d];
        float bias = l1_b[tid];
        #pragma unroll
        for (int r = 0; r < 4; ++r) {
            float acc = bias;
            #pragma unroll
            for (int d = 0; d < 64; ++d)
                acc += s_x[r * 64 + d] * w[d];
            s_a1[r * 256 + tid] = fmaxf(acc, 0.f);
        }
    }
    __syncthreads();
    {
        float acc[4];
        float bias = l2_b[tid];
        #pragma unroll
        for (int r = 0; r < 4; ++r) acc[r] = bias;
        for (int kc = 0; kc < 4; ++kc) {
            const float* wr = l2_w + tid * 256 + kc * 64;
            #pragma unroll
            for (int d = 0; d < 64; ++d) w[d] = wr[d];
            #pragma unroll
            for (int r = 0; r < 4; ++r) {
                #pragma unroll
                for (int d = 0; d < 64; ++d)
                    acc[r] += s_a1[r * 256 + kc * 64 + d] * w[d];
            }
        }
        #pragma unroll
        for (int r = 0; r < 4; ++r)
            s_a2[r * 260 + tid] = fmaxf(acc[r], 0.f);
    }
    __syncthreads();

    if (tid < 32) {
        int r = tid >> 3, o = tid & 7;
        float acc = l3_b[o];
        const float4* wr4 = (const float4*)(l3_w + o * 256);
        const float4* a4  = (const float4*)&s_a2[r * 260];
        #pragma unroll 8
        for (int k = 0; k < 64; ++k) {
            float4 av = a4[k];
            float4 wv = wr4[k];
            acc += av.x * wv.x + av.y * wv.y + av.z * wv.z + av.w * wv.w;
        }
        out[(size_t)(blockIdx.x * 4 + r) * 8 + o] =
            1.f / (1.f + __expf(-acc));
    }
}

// ---------------------------------------------------------------------------
extern "C" void kernel_launch(void* const* d_in, const int* in_sizes, int n_in,
                              void* d_out, int out_size, void* d_ws, size_t ws_size,
                              hipStream_t stream)
{
    const float* gs    = (const float*)d_in[0];
    const float* ls    = (const float*)d_in[1];
    const float* W_w   = (const float*)d_in[2];
    const float* W_b   = (const float*)d_in[3];
    const float* U_w   = (const float*)d_in[4];
    const float* U_b   = (const float*)d_in[5];
    const float* att_w = (const float*)d_in[6];
    const float* att_b = (const float*)d_in[7];
    const float* l1_w  = (const float*)d_in[8];
    const float* l1_b  = (const float*)d_in[9];
    const float* l2_w  = (const float*)d_in[10];
    const float* l2_b  = (const float*)d_in[11];
    const float* l3_w  = (const float*)d_in[12];
    const float* l3_b  = (const float*)d_in[13];

    const size_t need = (size_t)BB * 64 * sizeof(float);
    if (d_ws != nullptr && ws_size >= need) {
        float* states = (float*)d_ws;
        actor_stream_kernel<<<BB, 128, 0, stream>>>(
            gs, ls, W_w, W_b, U_w, U_b, att_w, att_b, states);
        actor_mlp_kernel<<<BB / 4, 256, 0, stream>>>(
            states, l1_w, l1_b, l2_w, l2_b, l3_w, l3_b, (float*)d_out);
    } else {
        actor_fused_kernel<<<BB / 4, 256, 0, stream>>>(
            gs, ls, W_w, W_b, U_w, U_b, att_w, att_b,
            l1_w, l1_b, l2_w, l2_b, l3_w, l3_b, (float*)d_out);
    }
}

// Round 2
// 395.287 us; speedup vs baseline: 1.0097x; 1.0097x over previous
//
#include <hip/hip_runtime.h>
#include <math.h>

#define BB 4096
#define LL 200
#define HH 32

// ---------------------------------------------------------------------------
// R5: single fused kernel (workspace abandoned — R4 showed the harness
// poisons d_ws with an 800-MiB fill *inside* the timed region, +125 us,
// plus 69 MB of dirty writebacks during our kernel).
//
// R4 post-mortem on the stream: occupancy 28%->77% bought only +11% BW
// (1.47->1.64 TB/s). NOT latency-bound: a ~1.6 TB/s wall on the VGPR
// global-load path. VGPR_Count=32 proved the PF=8 ring (needs 32 VGPRs
// for Xbuf alone) was collapsed by the compiler in BOTH rounds.
//
// Fix: change the path. Stage each row via global_load_lds width=16 DMA
// (the m93->m97 lever), double-buffered 5-KB groups per wave, counted
// s_waitcnt vmcnt(5) (T4). Outstanding bytes now live in LDS, not VGPRs:
// 5-10 KB/wave guaranteed in flight. Buffers are wave-private -> zero
// barriers in the stream loop.
//   LDS: 40 KB staging + ~10.5 KB MLP = 51.5 KB -> 3 blocks/CU,
//   12 waves/CU, 60-120 KB in flight per CU.
// ---------------------------------------------------------------------------

__device__ __forceinline__ void issue_group5(const float* src_lane,
                                             float* lds_dst)
{
    // 5 chunks x (64 lanes x 16 B) = 5 KB. LDS dst is wave-uniform base;
    // HW scatters lane*16. Source is per-lane (contiguous 1 KB per chunk).
    #pragma unroll
    for (int cc = 0; cc < 5; ++cc)
        __builtin_amdgcn_global_load_lds(
            (__attribute__((address_space(1))) const void*)(src_lane + cc * 256),
            (__attribute__((address_space(3))) void*)(lds_dst + cc * 256),
            16, 0, 0);
}

__global__ __launch_bounds__(256) void actor_fused_kernel(
    const float* __restrict__ gs,
    const float* __restrict__ ls,
    const float* __restrict__ W_w, const float* __restrict__ W_b,
    const float* __restrict__ U_w, const float* __restrict__ U_b,
    const float* __restrict__ att_w, const float* __restrict__ att_b,
    const float* __restrict__ l1_w, const float* __restrict__ l1_b,
    const float* __restrict__ l2_w, const float* __restrict__ l2_b,
    const float* __restrict__ l3_w, const float* __restrict__ l3_b,
    float* __restrict__ out)
{
    __shared__ __align__(16) float stage[4][2][1280];  // 40 KB: per-wave dbuf
    __shared__ float c_lds[64];
    __shared__ __align__(16) float y_lds[4][64];
    __shared__ __align__(16) float s_x [4 * 64];
    __shared__ __align__(16) float s_a1[4 * 256];
    __shared__ __align__(16) float s_a2[4 * 260];  // pad 260: float4-able

    const int tid  = threadIdx.x;
    const int lane = tid & 63;
    const int wid  = tid >> 6;
    const int b    = blockIdx.x * 4 + wid;

    const int h    = lane & 31;   // owned hidden unit (both halves)
    const int half = lane >> 5;   // d-half for 64-d dots
    const int q    = lane & 15;   // d-quad within l-group

    // ================= Phase A: attention pooling (per wave) =================

    // ---- wg[h] = gs[b].W_w[h] + W_b[h]; halves split d, xor32 combine ----
    const float4* g4 = (const float4*)(gs + (size_t)b * 64);
    const float4* W4 = (const float4*)(W_w);
    float wg = (half == 0) ? W_b[h] : 0.f;
    #pragma unroll
    for (int dd = 0; dd < 8; ++dd) {
        float4 gv = g4[half * 8 + dd];
        float4 wv = W4[h * 16 + half * 8 + dd];
        wg += gv.x * wv.x + gv.y * wv.y + gv.z * wv.z + gv.w * wv.w;
    }
    wg += __shfl_xor(wg, 32);     // all lanes now hold wg[h]

    // ---- gt = wg.a_g ; t2 = wg.a_l (butterfly over h within 32-halves) ----
    float gt = wg * att_w[h];
    float t2 = wg * att_w[HH + h];
    #pragma unroll
    for (int m = 1; m < 32; m <<= 1) {
        gt += __shfl_xor(gt, m);
        t2 += __shfl_xor(t2, m);
    }
    const float attb = att_b[0];
    const float lin0 = gt + t2 + attb;
    const float s0   = (lin0 > 0.f) ? lin0 : 0.01f * lin0;

    // ---- c[d] = sum_h a_l[h]*U_w[h][d]  (b-independent; lane owns d) ----
    float c = 0.f;
    float ubal = 0.f;
    #pragma unroll
    for (int hh = 0; hh < HH; ++hh) {
        const float alh = att_w[HH + hh];        // uniform -> s_load
        c    += alh * U_w[hh * 64 + lane];       // coalesced, L1-hot
        ubal += alh * U_b[hh];
    }
    c_lds[lane] = c;                 // all waves write identical values
    __syncthreads();
    const float4 cq = *(const float4*)&c_lds[4 * q];
    const float base = gt + ubal + attb;

    // ---- stream: 50 chunks (10 groups x 5 KB), DMA double-buffer ----
    const float* rowp = ls + (size_t)b * (LL * 64);
    float* bufA = &stage[wid][0][0];
    float* bufB = &stage[wid][1][0];

    // Clean vmcnt slate so the counted waits below see ONLY our DMA ops.
    asm volatile("s_waitcnt vmcnt(0)" ::: "memory");

    issue_group5(rowp + 0 * 1280 + (lane << 2), bufA);
    issue_group5(rowp + 1 * 1280 + (lane << 2), bufB);

    float4 yx = make_float4(0.f, 0.f, 0.f, 0.f);
    float Sacc = 0.f;

    #pragma unroll
    for (int g = 0; g < 10; ++g) {
        const float* cur = (g & 1) ? bufB : bufA;
        if (g < 9) asm volatile("s_waitcnt vmcnt(5)" ::: "memory");
        else       asm volatile("s_waitcnt vmcnt(0)" ::: "memory");
        __builtin_amdgcn_sched_barrier(0);   // no ds_read hoists above wait

        #pragma unroll
        for (int cc = 0; cc < 5; ++cc) {
            float4 X = ((const float4*)cur)[cc * 64 + lane];  // ds_read_b128
            float p = X.x * cq.x + X.y * cq.y + X.z * cq.z + X.w * cq.w;
            p += __shfl_xor(p, 1);
            p += __shfl_xor(p, 2);
            p += __shfl_xor(p, 4);
            p += __shfl_xor(p, 8);      // 16-lane group dot: x[l].c
            const float linv = p + base;
            const float sl = (linv > 0.f) ? linv : 0.01f * linv;
            yx.x += sl * X.x;
            yx.y += sl * X.y;
            yx.z += sl * X.z;
            yx.w += sl * X.w;
            Sacc += sl;                 // identical across the 16-lane group
        }

        __builtin_amdgcn_sched_barrier(0);   // DMA refill must not pass reads
        if (g < 8)
            issue_group5(rowp + (g + 2) * 1280 + (lane << 2),
                         (g & 1) ? bufB : bufA);
    }

    // ---- combine the 4 l-groups ----
    #pragma unroll
    for (int m = 16; m < 64; m <<= 1) {
        yx.x += __shfl_xor(yx.x, m);
        yx.y += __shfl_xor(yx.y, m);
        yx.z += __shfl_xor(yx.z, m);
        yx.w += __shfl_xor(yx.w, m);
        Sacc += __shfl_xor(Sacc, m);
    }
    if (lane < 16) *(float4*)&y_lds[wid][4 * q] = yx;
    __syncthreads();

    // ---- V[h] = U_w[h].y + U_b[h]*S ----
    float V = (half == 0) ? (U_b[h] * Sacc) : 0.f;
    const float4* U4 = (const float4*)U_w;
    const float4* y4 = (const float4*)&y_lds[wid][0];
    #pragma unroll
    for (int dd = 0; dd < 8; ++dd) {
        float4 uv = U4[h * 16 + half * 8 + dd];
        float4 yv = y4[half * 8 + dd];
        V += uv.x * yv.x + uv.y * yv.y + uv.z * yv.z + uv.w * yv.w;
    }
    V += __shfl_xor(V, 32);        // all lanes hold full V[h]

    const float total = s0 + Sacc;
    const float n0    = s0 / total;
    const float outv  = (lane < 32) ? (n0 * wg) : (V / total);
    s_x[wid * 64 + lane] = fmaxf(outv, 0.f);   // states -> LDS
    __syncthreads();

    // ================= Phase B: MLP 64->256->256->8 (block-wide) =============

    float w[64];

    // ---- layer 1: thread owns unit tid; weight row in VGPRs ----
    {
        const float* wr = l1_w + tid * 64;
        #pragma unroll
        for (int d = 0; d < 64; ++d) w[d] = wr[d];
        float bias = l1_b[tid];
        #pragma unroll
        for (int r = 0; r < 4; ++r) {
            float acc = bias;
            #pragma unroll
            for (int d = 0; d < 64; ++d)
                acc += s_x[r * 64 + d] * w[d];   // LDS broadcast
            s_a1[r * 256 + tid] = fmaxf(acc, 0.f);
        }
    }
    __syncthreads();

    // ---- layer 2 ----
    {
        float acc[4];
        float bias = l2_b[tid];
        #pragma unroll
        for (int r = 0; r < 4; ++r) acc[r] = bias;
        for (int kc = 0; kc < 4; ++kc) {
            const float* wr = l2_w + tid * 256 + kc * 64;
            #pragma unroll
            for (int d = 0; d < 64; ++d) w[d] = wr[d];
            #pragma unroll
            for (int r = 0; r < 4; ++r) {
                #pragma unroll
                for (int d = 0; d < 64; ++d)
                    acc[r] += s_a1[r * 256 + kc * 64 + d] * w[d];
            }
        }
        #pragma unroll
        for (int r = 0; r < 4; ++r)
            s_a2[r * 260 + tid] = fmaxf(acc[r], 0.f);
    }
    __syncthreads();

    // ---- layer 3 + sigmoid: threads 0..31, float4 LDS reads ----
    if (tid < 32) {
        int r = tid >> 3, o = tid & 7;
        float acc = l3_b[o];
        const float4* wr4 = (const float4*)(l3_w + o * 256);
        const float4* a4  = (const float4*)&s_a2[r * 260];
        #pragma unroll 8
        for (int k = 0; k < 64; ++k) {
            float4 av = a4[k];
            float4 wv = wr4[k];
            acc += av.x * wv.x + av.y * wv.y + av.z * wv.z + av.w * wv.w;
        }
        out[(size_t)(blockIdx.x * 4 + r) * 8 + o] =
            1.f / (1.f + __expf(-acc));   // MAX_ACTION = 1
    }
}

// ---------------------------------------------------------------------------
extern "C" void kernel_launch(void* const* d_in, const int* in_sizes, int n_in,
                              void* d_out, int out_size, void* d_ws, size_t ws_size,
                              hipStream_t stream)
{
    const float* gs    = (const float*)d_in[0];
    const float* ls    = (const float*)d_in[1];
    const float* W_w   = (const float*)d_in[2];
    const float* W_b   = (const float*)d_in[3];
    const float* U_w   = (const float*)d_in[4];
    const float* U_b   = (const float*)d_in[5];
    const float* att_w = (const float*)d_in[6];
    const float* att_b = (const float*)d_in[7];
    const float* l1_w  = (const float*)d_in[8];
    const float* l1_b  = (const float*)d_in[9];
    const float* l2_w  = (const float*)d_in[10];
    const float* l2_b  = (const float*)d_in[11];
    const float* l3_w  = (const float*)d_in[12];
    const float* l3_b  = (const float*)d_in[13];

    actor_fused_kernel<<<BB / 4, 256, 0, stream>>>(
        gs, ls, W_w, W_b, U_w, U_b, att_w, att_b,
        l1_w, l1_b, l2_w, l2_b, l3_w, l3_b, (float*)d_out);
}